// Round 6
// baseline (196.699 us; speedup 1.0000x reference)
//
#include <hip/hip_runtime.h>

typedef __bf16 bf16;
typedef __bf16 bf16x8 __attribute__((ext_vector_type(8)));
typedef float  f32x4  __attribute__((ext_vector_type(4)));

#define T_SEQ   2048
#define D_HEAD  64
#define NH      16
#define BH      32
#define C_EMB   1024
#define WS_STRIDE (BH * T_SEQ * D_HEAD)   // 4,194,304 elems per plane
#define XN (4096 * 1024)
#define WN (3072 * 1024)
#define WS_NEEDED ((size_t)(3 * WS_STRIDE + XN + WN) * 2)
#define OUT_F4 1048576                    // out floats / 4
#define CVT_GRID 3584

__device__ __forceinline__ bf16x8 cvt8(float4 a, float4 b) {
    bf16x8 r;
    r[0] = (__bf16)a.x; r[1] = (__bf16)a.y; r[2] = (__bf16)a.z; r[3] = (__bf16)a.w;
    r[4] = (__bf16)b.x; r[5] = (__bf16)b.y; r[6] = (__bf16)b.z; r[7] = (__bf16)b.w;
    return r;
}

__device__ __forceinline__ void gl_lds16(const bf16* g, bf16* l) {
    __builtin_amdgcn_global_load_lds(
        (const __attribute__((address_space(1))) unsigned int*)g,
        (__attribute__((address_space(3))) unsigned int*)l,
        16, 0, 0);
}

__device__ __forceinline__ unsigned pack_bf16(float a, float b) {
    union { __bf16 h[2]; unsigned u; } pk;
    pk.h[0] = (__bf16)a; pk.h[1] = (__bf16)b;
    return pk.u;
}

// ---------------------------------------------------------------------------
// Kernel 0: fp32 -> bf16 convert of x and W; also zeroes `out`.
// ---------------------------------------------------------------------------
__global__ __launch_bounds__(256) void cvt_bf16(
    const float* __restrict__ x, const float* __restrict__ W,
    bf16* __restrict__ xb, bf16* __restrict__ wb, float* __restrict__ out)
{
    const int t = blockIdx.x * 256 + threadIdx.x;   // 917504 threads
    {
        float4 z = {0.f, 0.f, 0.f, 0.f};
        for (int i = t; i < OUT_F4; i += CVT_GRID * 256)
            ((float4*)out)[i] = z;
    }
    const float* src; bf16* dst; int base;
    if (t < XN / 8) { src = x; dst = xb; base = t * 8; }
    else           { src = W; dst = wb; base = (t - XN / 8) * 8; }
    float4 a = *(const float4*)(src + base);
    float4 b = *(const float4*)(src + base + 4);
    *(bf16x8*)(dst + base) = cvt8(a, b);
}

// ---------------------------------------------------------------------------
// Kernel 1: qkv = xb @ wb^T + b. BK=64, XOR-swizzled LDS staging via
// global_load_lds w=16. Epilogue: LDS-transpose -> coalesced b128 stores.
// q plane pre-scaled by 0.125; v plane written transposed vt[bh][d][t].
// ---------------------------------------------------------------------------
__global__ __launch_bounds__(256) void qkv_gemm2(
    const bf16* __restrict__ xb, const bf16* __restrict__ wb,
    const float* __restrict__ bias, bf16* __restrict__ ws)
{
    __shared__ bf16 Sh[2 * 128 * 64];     // main loop: As|Bs; epilogue: 128x128
    bf16* As = Sh;
    bf16* Bs = Sh + 128 * 64;

    const int tid  = threadIdx.x;
    const int lane = tid & 63;
    const int w    = tid >> 6;
    const int wm   = w >> 1, wn = w & 1;
    const int l15  = lane & 15, l4 = lane >> 4;
    const int bm   = blockIdx.x / 24, bn = blockIdx.x % 24;

    const int srow  = lane >> 3;            // 0..7
    const int csrc  = (lane & 7) ^ srow;    // XOR-swizzled global chunk
    const bf16* ag = xb + (size_t)(bm * 128 + w * 32 + srow) * 1024 + csrc * 8;
    const bf16* bg = wb + (size_t)(bn * 128 + w * 32 + srow) * 1024 + csrc * 8;
    bf16* al = &As[w * 2048];
    bf16* bl = &Bs[w * 2048];

    f32x4 acc[4][4];
#pragma unroll
    for (int i = 0; i < 4; i++)
#pragma unroll
        for (int j = 0; j < 4; j++) acc[i][j] = (f32x4){0.f, 0.f, 0.f, 0.f};

    float bv[4];
#pragma unroll
    for (int j = 0; j < 4; j++) bv[j] = bias[bn * 128 + wn * 64 + j * 16 + l15];

    for (int kk = 0; kk < 16; ++kk) {
        __syncthreads();   // prev iteration's fragment reads complete
#pragma unroll
        for (int e = 0; e < 4; e++) {
            gl_lds16(ag + kk * 64 + e * 8 * 1024, al + e * 512);
            gl_lds16(bg + kk * 64 + e * 8 * 1024, bl + e * 512);
        }
        __syncthreads();   // drains vmcnt -> staging visible

        bf16x8 aF[4][2], bF[4][2];
#pragma unroll
        for (int s = 0; s < 4; s++) {
#pragma unroll
            for (int dk = 0; dk < 2; dk++) {
                const int ra = wm * 64 + s * 16 + l15;
                const int rb = wn * 64 + s * 16 + l15;
                aF[s][dk] = *(const bf16x8*)&As[ra * 64 + (((dk * 4 + l4) ^ (ra & 7)) * 8)];
                bF[s][dk] = *(const bf16x8*)&Bs[rb * 64 + (((dk * 4 + l4) ^ (rb & 7)) * 8)];
            }
        }
#pragma unroll
        for (int dk = 0; dk < 2; dk++)
#pragma unroll
            for (int i = 0; i < 4; i++)
#pragma unroll
                for (int j = 0; j < 4; j++)
                    acc[i][j] = __builtin_amdgcn_mfma_f32_16x16x32_bf16(
                        aF[i][dk], bF[j][dk], acc[i][j], 0, 0, 0);
    }

    // ---- epilogue: +bias (+0.125 scale for q); LDS transpose -> b128 stores
    __syncthreads();                       // all fragment reads done
    const int which = bn >> 3;             // 0=q, 1=k, 2=v (block-uniform)
    const int bi    = bm >> 4;             // batch (block-uniform)
    const int tloc  = (bm & 15) * 128;     // t-offset within this batch
    const float qs  = (which == 0) ? 0.125f : 1.0f;

    if (which < 2) {
        // store tile as [m][n], 16B-chunk swizzle: (m,n) -> m*128 + ((n>>3)^swz)*8 + (n&7)
#pragma unroll
        for (int i = 0; i < 4; i++) {
#pragma unroll
            for (int j = 0; j < 4; j++) {
                const int n = wn * 64 + j * 16 + l15;
                const int c = n >> 3;
#pragma unroll
                for (int r = 0; r < 4; r++) {
                    const int m  = wm * 64 + i * 16 + l4 * 4 + r;
                    const int cp = (c & 8) | ((c & 7) ^ (m & 7));
                    Sh[m * 128 + cp * 8 + (n & 7)] = (__bf16)((acc[i][j][r] + bv[j]) * qs);
                }
            }
        }
        __syncthreads();
#pragma unroll
        for (int it = 0; it < 8; it++) {
            const int m  = it * 16 + (tid >> 4);
            const int c  = tid & 15;
            const int cp = (c & 8) | ((c & 7) ^ (m & 7));
            bf16x8 v8 = *(const bf16x8*)&Sh[m * 128 + cp * 8];
            const int nl = c * 8;
            const int h  = (bn & 7) * 2 + (nl >> 6);
            const int d  = nl & 63;
            const int t  = tloc + m;
            *(bf16x8*)&ws[(size_t)which * WS_STRIDE
                          + ((size_t)(bi * NH + h) * T_SEQ + t) * D_HEAD + d] = v8;
        }
    } else {
        // v: store tile as [n][m], 16B-chunk swizzle on m; dword-packed writes
#pragma unroll
        for (int i = 0; i < 4; i++) {
#pragma unroll
            for (int j = 0; j < 4; j++) {
                const int n = wn * 64 + j * 16 + l15;
#pragma unroll
                for (int p = 0; p < 2; p++) {
                    const int m0 = wm * 64 + i * 16 + l4 * 4 + 2 * p;
                    const int ch = m0 >> 3;
                    const int cp = (ch & 8) | ((ch & 7) ^ (n & 7));
                    *(unsigned*)&Sh[n * 128 + cp * 8 + (m0 & 7)] =
                        pack_bf16(acc[i][j][2 * p] + bv[j], acc[i][j][2 * p + 1] + bv[j]);
                }
            }
        }
        __syncthreads();
        bf16* vt = ws + 2 * (size_t)WS_STRIDE;
#pragma unroll
        for (int it = 0; it < 8; it++) {
            const int n  = it * 16 + (tid >> 4);
            const int mc = tid & 15;
            const int cp = (mc & 8) | ((mc & 7) ^ (n & 7));
            bf16x8 v8 = *(const bf16x8*)&Sh[n * 128 + cp * 8];
            const int h  = (bn & 7) * 2 + (n >> 6);
            const int d  = n & 63;
            const int t  = tloc + mc * 8;
            *(bf16x8*)&vt[((size_t)(bi * NH + h) * D_HEAD + d) * T_SEQ + t] = v8;
        }
    }
}

// ---------------------------------------------------------------------------
// Kernel 1 fallback (ws too small): register-convert GEMM, scalar epilogue.
// ---------------------------------------------------------------------------
__global__ __launch_bounds__(256) void qkv_gemm(
    const float* __restrict__ x, const float* __restrict__ W,
    const float* __restrict__ bias, bf16* __restrict__ ws,
    float* __restrict__ out)
{
    __shared__ bf16 As[128 * 40];
    __shared__ bf16 Bs[128 * 40];

    const int tid  = threadIdx.x;
    const int lane = tid & 63;
    const int w    = tid >> 6;
    const int wm   = w >> 1, wn = w & 1;
    const int l15  = lane & 15, l4 = lane >> 4;
    const int bm   = blockIdx.x / 24, bn = blockIdx.x % 24;

    {
        float4 z = {0.f, 0.f, 0.f, 0.f};
        for (int i = blockIdx.x * 256 + tid; i < OUT_F4; i += 768 * 256)
            ((float4*)out)[i] = z;
    }

    const int srow = tid >> 1;
    const int scol = (tid & 1) * 16;
    const float* xg = x + (size_t)(bm * 128 + srow) * 1024 + scol;
    const float* wg = W + (size_t)(bn * 128 + srow) * 1024 + scol;
    bf16* asw = &As[srow * 40 + scol];
    bf16* bsw = &Bs[srow * 40 + scol];

    f32x4 acc[4][4];
#pragma unroll
    for (int i = 0; i < 4; i++)
#pragma unroll
        for (int j = 0; j < 4; j++) acc[i][j] = (f32x4){0.f, 0.f, 0.f, 0.f};

    float bv[4];
#pragma unroll
    for (int j = 0; j < 4; j++) bv[j] = bias[bn * 128 + wn * 64 + j * 16 + l15];

    for (int kk = 0; kk < 32; ++kk) {
        const float* xp = xg + kk * 32;
        const float* wp = wg + kk * 32;
        float4 a0 = *(const float4*)(xp + 0);
        float4 a1 = *(const float4*)(xp + 4);
        float4 a2 = *(const float4*)(xp + 8);
        float4 a3 = *(const float4*)(xp + 12);
        float4 b0 = *(const float4*)(wp + 0);
        float4 b1 = *(const float4*)(wp + 4);
        float4 b2 = *(const float4*)(wp + 8);
        float4 b3 = *(const float4*)(wp + 12);

        __syncthreads();
        *(bf16x8*)(asw + 0) = cvt8(a0, a1);
        *(bf16x8*)(asw + 8) = cvt8(a2, a3);
        *(bf16x8*)(bsw + 0) = cvt8(b0, b1);
        *(bf16x8*)(bsw + 8) = cvt8(b2, b3);
        __syncthreads();

        bf16x8 aF[4], bF[4];
#pragma unroll
        for (int s = 0; s < 4; s++) {
            aF[s] = *(const bf16x8*)&As[(wm * 64 + s * 16 + l15) * 40 + l4 * 8];
            bF[s] = *(const bf16x8*)&Bs[(wn * 64 + s * 16 + l15) * 40 + l4 * 8];
        }
#pragma unroll
        for (int i = 0; i < 4; i++)
#pragma unroll
            for (int j = 0; j < 4; j++)
                acc[i][j] = __builtin_amdgcn_mfma_f32_16x16x32_bf16(
                    aF[i], bF[j], acc[i][j], 0, 0, 0);
    }

#pragma unroll
    for (int i = 0; i < 4; i++) {
#pragma unroll
        for (int j = 0; j < 4; j++) {
            const int n     = bn * 128 + wn * 64 + j * 16 + l15;
            const int which = n >> 10;
            const int cc    = n & 1023;
            const int h     = cc >> 6, d = cc & 63;
            const float qs  = (which == 0) ? 0.125f : 1.0f;
#pragma unroll
            for (int r = 0; r < 4; r++) {
                const int m  = bm * 128 + wm * 64 + i * 16 + l4 * 4 + r;
                const int bi = m >> 11, t = m & 2047;
                const int bh = bi * NH + h;
                const float v = (acc[i][j][r] + bv[j]) * qs;
                size_t idx;
                if (which == 2)
                    idx = 2 * (size_t)WS_STRIDE + ((size_t)bh * D_HEAD + d) * T_SEQ + t;
                else
                    idx = (size_t)which * WS_STRIDE + ((size_t)bh * T_SEQ + t) * D_HEAD + d;
                ws[idx] = (__bf16)v;
            }
        }
    }
}

// ---------------------------------------------------------------------------
// Kernel 2: causal ReLU attention — no LDS, no barriers, no cross-lane P xfer.
// K rows loaded PERMUTED (bit-field swap) so S^T's C-registers are directly
// the PV A-fragments: key(kn,m) = 32*(kn>>1) + 8*(m>>2) + 4*(kn&1) + (m&3).
// q pre-scaled by 1/8 in the GEMM. 2-way key split, atomicAdd combine.
// ---------------------------------------------------------------------------
__global__ __launch_bounds__(256) void attn(
    const bf16* __restrict__ ws, float* __restrict__ out)
{
    const int tid  = threadIdx.x;
    const int lane = tid & 63;
    const int w    = tid >> 6;
    const int l15  = lane & 15, qd = lane >> 4;

    const int bh   = blockIdx.x & 31;      // XCD = blk&7 -> bh mod 8 affinity
    const int rest = blockIdx.x >> 5;      // 0..31
    const int qt   = rest >> 1;            // 0..15
    const int half = rest & 1;

    const bf16* qg = ws + (size_t)bh * (T_SEQ * D_HEAD);
    const bf16* kg = ws + WS_STRIDE + (size_t)bh * (T_SEQ * D_HEAD);
    const bf16* vt = ws + 2 * (size_t)WS_STRIDE + (size_t)bh * (D_HEAD * T_SEQ);
    const int qbase = qt * 128;

    // Q fragments (pre-scaled by 1/8): live across whole loop
    bf16x8 qF[2][2];
#pragma unroll
    for (int sm = 0; sm < 2; sm++)
#pragma unroll
        for (int dk = 0; dk < 2; dk++)
            qF[sm][dk] = *(const bf16x8*)(qg + (qbase + w * 32 + sm * 16 + l15) * 64
                                          + dk * 32 + qd * 8);

    f32x4 o[2][4];
#pragma unroll
    for (int sm = 0; sm < 2; sm++)
#pragma unroll
        for (int sd = 0; sd < 4; sd++) o[sm][sd] = (f32x4){0.f, 0.f, 0.f, 0.f};

    // permuted K row base for this lane (m = l15)
    const int rlo = ((l15 >> 2) << 3) | (l15 & 3);

    const int jt0 = half * (qt + 1);
    const int jt1 = jt0 + qt;
    for (int jt = jt0; jt <= jt1; ++jt) {
        const bf16* kb = kg + (size_t)jt * 64 * 64;
        const bf16* vb = vt + jt * 64;

        // ---- K fragments, permuted rows ----
        bf16x8 kF[4][2];
#pragma unroll
        for (int kn = 0; kn < 4; kn++) {
            const int row = ((kn >> 1) << 5) + ((kn & 1) << 2) + rlo;
#pragma unroll
            for (int dk = 0; dk < 2; dk++)
                kF[kn][dk] = *(const bf16x8*)(kb + row * 64 + dk * 32 + qd * 8);
        }
        // ---- V fragments from transposed plane: B[k=key][n=d] ----
        bf16x8 vF[4][2];
#pragma unroll
        for (int sd = 0; sd < 4; sd++)
#pragma unroll
            for (int kk = 0; kk < 2; kk++)
                vF[sd][kk] = *(const bf16x8*)(vb + (size_t)(sd * 16 + l15) * T_SEQ
                                              + kk * 32 + qd * 8);

        // ---- S^T = K' Q^T (scaled already) ----
        f32x4 sT[4][2];
#pragma unroll
        for (int kn = 0; kn < 4; kn++)
#pragma unroll
            for (int sm = 0; sm < 2; sm++) sT[kn][sm] = (f32x4){0.f, 0.f, 0.f, 0.f};
#pragma unroll
        for (int kn = 0; kn < 4; kn++)
#pragma unroll
            for (int dk = 0; dk < 2; dk++)
#pragma unroll
                for (int sm = 0; sm < 2; sm++)
                    sT[kn][sm] = __builtin_amdgcn_mfma_f32_16x16x32_bf16(
                        kF[kn][dk], qF[sm][dk], sT[kn][sm], 0, 0, 0);

        // ---- relu + causal mask + pack (keys are the permuted ones) ----
        const bool need_mask = (jt >= 2 * qt);
        unsigned PK[2][4][2];
#pragma unroll
        for (int sm = 0; sm < 2; sm++) {
            const int q = qbase + w * 32 + sm * 16 + l15;
#pragma unroll
            for (int kn = 0; kn < 4; kn++) {
                float v[4];
#pragma unroll
                for (int r = 0; r < 4; r++) {
                    float val = fmaxf(sT[kn][sm][r], 0.f);
                    if (need_mask) {
                        const int key = jt * 64 + ((kn >> 1) << 5) + ((kn & 1) << 2)
                                        + qd * 8 + r;
                        if (q < key) val = 0.f;
                    }
                    v[r] = val;
                }
                PK[sm][kn][0] = pack_bf16(v[0], v[1]);
                PK[sm][kn][1] = pack_bf16(v[2], v[3]);
            }
        }

        // ---- O += P V : pF comes straight from this lane's PK dwords ----
#pragma unroll
        for (int kk = 0; kk < 2; kk++) {
            bf16x8 pF[2];
#pragma unroll
            for (int sm = 0; sm < 2; sm++) {
                union { unsigned dw[4]; bf16x8 v; } u;
                u.dw[0] = PK[sm][2 * kk + 0][0];
                u.dw[1] = PK[sm][2 * kk + 0][1];
                u.dw[2] = PK[sm][2 * kk + 1][0];
                u.dw[3] = PK[sm][2 * kk + 1][1];
                pF[sm] = u.v;
            }
#pragma unroll
            for (int sd = 0; sd < 4; sd++)
#pragma unroll
                for (int sm = 0; sm < 2; sm++)
                    o[sm][sd] = __builtin_amdgcn_mfma_f32_16x16x32_bf16(
                        pF[sm], vF[sd][kk], o[sm][sd], 0, 0, 0);
        }
    }

    // ---- epilogue: atomic-accumulate O into out[b][t][h*64+d] ----
    const int b = bh >> 4, h = bh & 15;
#pragma unroll
    for (int sm = 0; sm < 2; sm++) {
#pragma unroll
        for (int sd = 0; sd < 4; sd++) {
            const int d = sd * 16 + l15;
#pragma unroll
            for (int r = 0; r < 4; r++) {
                const int t = qbase + w * 32 + sm * 16 + qd * 4 + r;
                unsafeAtomicAdd(&out[((size_t)b * T_SEQ + t) * C_EMB + h * 64 + d],
                                o[sm][sd][r]);
            }
        }
    }
}

extern "C" void kernel_launch(void* const* d_in, const int* in_sizes, int n_in,
                              void* d_out, int out_size, void* d_ws, size_t ws_size,
                              hipStream_t stream) {
    const float* x    = (const float*)d_in[0];
    const float* W    = (const float*)d_in[1];
    const float* bias = (const float*)d_in[2];
    float* out        = (float*)d_out;
    bf16*  ws         = (bf16*)d_ws;

    if (ws_size >= WS_NEEDED) {
        bf16* xb = ws + 3 * (size_t)WS_STRIDE;
        bf16* wb = xb + XN;
        cvt_bf16<<<dim3(CVT_GRID), dim3(256), 0, stream>>>(x, W, xb, wb, out);
        qkv_gemm2<<<dim3(768), dim3(256), 0, stream>>>(xb, wb, bias, ws);
    } else {
        qkv_gemm<<<dim3(768), dim3(256), 0, stream>>>(x, W, bias, ws, out);
    }
    attn<<<dim3(1024), dim3(256), 0, stream>>>(ws, out);
}

// Round 7
// 170.488 us; speedup vs baseline: 1.1537x; 1.1537x over previous
//
#include <hip/hip_runtime.h>

typedef __bf16 bf16;
typedef __bf16 bf16x8 __attribute__((ext_vector_type(8)));
typedef float  f32x4  __attribute__((ext_vector_type(4)));

#define T_SEQ   2048
#define D_HEAD  64
#define NH      16
#define BH      32
#define C_EMB   1024
#define WS_STRIDE (BH * T_SEQ * D_HEAD)   // 4,194,304 elems per plane
#define XN (4096 * 1024)
#define WN (3072 * 1024)
#define WS_NEEDED ((size_t)(3 * WS_STRIDE + XN + WN) * 2)
#define OUT_F4 1048576                    // out floats / 4
#define CVT_GRID 3584

__device__ __forceinline__ bf16x8 cvt8(float4 a, float4 b) {
    bf16x8 r;
    r[0] = (__bf16)a.x; r[1] = (__bf16)a.y; r[2] = (__bf16)a.z; r[3] = (__bf16)a.w;
    r[4] = (__bf16)b.x; r[5] = (__bf16)b.y; r[6] = (__bf16)b.z; r[7] = (__bf16)b.w;
    return r;
}

__device__ __forceinline__ void gl_lds16(const bf16* g, bf16* l) {
    __builtin_amdgcn_global_load_lds(
        (const __attribute__((address_space(1))) unsigned int*)g,
        (__attribute__((address_space(3))) unsigned int*)l,
        16, 0, 0);
}

__device__ __forceinline__ unsigned pack_bf16(float a, float b) {
    union { __bf16 h[2]; unsigned u; } pk;
    pk.h[0] = (__bf16)a; pk.h[1] = (__bf16)b;
    return pk.u;
}

// ---------------------------------------------------------------------------
// Kernel 0: fp32 -> bf16 convert of x and W; also zeroes `out`.
// ---------------------------------------------------------------------------
__global__ __launch_bounds__(256) void cvt_bf16(
    const float* __restrict__ x, const float* __restrict__ W,
    bf16* __restrict__ xb, bf16* __restrict__ wb, float* __restrict__ out)
{
    const int t = blockIdx.x * 256 + threadIdx.x;   // 917504 threads
    {
        float4 z = {0.f, 0.f, 0.f, 0.f};
        for (int i = t; i < OUT_F4; i += CVT_GRID * 256)
            ((float4*)out)[i] = z;
    }
    const float* src; bf16* dst; int base;
    if (t < XN / 8) { src = x; dst = xb; base = t * 8; }
    else           { src = W; dst = wb; base = (t - XN / 8) * 8; }
    float4 a = *(const float4*)(src + base);
    float4 b = *(const float4*)(src + base + 4);
    *(bf16x8*)(dst + base) = cvt8(a, b);
}

// ---------------------------------------------------------------------------
// Kernel 1: qkv = xb @ wb^T + b. BK=64, XOR-swizzled LDS staging via
// global_load_lds w=16. Epilogue: LDS-transpose -> coalesced b128 stores.
// q plane pre-scaled by 0.125; v plane written transposed vt[bh][d][t].
// ---------------------------------------------------------------------------
__global__ __launch_bounds__(256) void qkv_gemm2(
    const bf16* __restrict__ xb, const bf16* __restrict__ wb,
    const float* __restrict__ bias, bf16* __restrict__ ws)
{
    __shared__ bf16 Sh[2 * 128 * 64];     // main loop: As|Bs; epilogue: 128x128
    bf16* As = Sh;
    bf16* Bs = Sh + 128 * 64;

    const int tid  = threadIdx.x;
    const int lane = tid & 63;
    const int w    = tid >> 6;
    const int wm   = w >> 1, wn = w & 1;
    const int l15  = lane & 15, l4 = lane >> 4;
    const int bm   = blockIdx.x / 24, bn = blockIdx.x % 24;

    const int srow  = lane >> 3;            // 0..7
    const int csrc  = (lane & 7) ^ srow;    // XOR-swizzled global chunk
    const bf16* ag = xb + (size_t)(bm * 128 + w * 32 + srow) * 1024 + csrc * 8;
    const bf16* bg = wb + (size_t)(bn * 128 + w * 32 + srow) * 1024 + csrc * 8;
    bf16* al = &As[w * 2048];
    bf16* bl = &Bs[w * 2048];

    f32x4 acc[4][4];
#pragma unroll
    for (int i = 0; i < 4; i++)
#pragma unroll
        for (int j = 0; j < 4; j++) acc[i][j] = (f32x4){0.f, 0.f, 0.f, 0.f};

    float bv[4];
#pragma unroll
    for (int j = 0; j < 4; j++) bv[j] = bias[bn * 128 + wn * 64 + j * 16 + l15];

    for (int kk = 0; kk < 16; ++kk) {
        __syncthreads();   // prev iteration's fragment reads complete
#pragma unroll
        for (int e = 0; e < 4; e++) {
            gl_lds16(ag + kk * 64 + e * 8 * 1024, al + e * 512);
            gl_lds16(bg + kk * 64 + e * 8 * 1024, bl + e * 512);
        }
        __syncthreads();   // drains vmcnt -> staging visible

        bf16x8 aF[4][2], bF[4][2];
#pragma unroll
        for (int s = 0; s < 4; s++) {
#pragma unroll
            for (int dk = 0; dk < 2; dk++) {
                const int ra = wm * 64 + s * 16 + l15;
                const int rb = wn * 64 + s * 16 + l15;
                aF[s][dk] = *(const bf16x8*)&As[ra * 64 + (((dk * 4 + l4) ^ (ra & 7)) * 8)];
                bF[s][dk] = *(const bf16x8*)&Bs[rb * 64 + (((dk * 4 + l4) ^ (rb & 7)) * 8)];
            }
        }
#pragma unroll
        for (int dk = 0; dk < 2; dk++)
#pragma unroll
            for (int i = 0; i < 4; i++)
#pragma unroll
                for (int j = 0; j < 4; j++)
                    acc[i][j] = __builtin_amdgcn_mfma_f32_16x16x32_bf16(
                        aF[i][dk], bF[j][dk], acc[i][j], 0, 0, 0);
    }

    // ---- epilogue: +bias (+0.125 scale for q); LDS transpose -> b128 stores
    __syncthreads();                       // all fragment reads done
    const int which = bn >> 3;             // 0=q, 1=k, 2=v (block-uniform)
    const int bi    = bm >> 4;             // batch (block-uniform)
    const int tloc  = (bm & 15) * 128;     // t-offset within this batch
    const float qs  = (which == 0) ? 0.125f : 1.0f;

    if (which < 2) {
#pragma unroll
        for (int i = 0; i < 4; i++) {
#pragma unroll
            for (int j = 0; j < 4; j++) {
                const int n = wn * 64 + j * 16 + l15;
                const int c = n >> 3;
#pragma unroll
                for (int r = 0; r < 4; r++) {
                    const int m  = wm * 64 + i * 16 + l4 * 4 + r;
                    const int cp = (c & 8) | ((c & 7) ^ (m & 7));
                    Sh[m * 128 + cp * 8 + (n & 7)] = (__bf16)((acc[i][j][r] + bv[j]) * qs);
                }
            }
        }
        __syncthreads();
#pragma unroll
        for (int it = 0; it < 8; it++) {
            const int m  = it * 16 + (tid >> 4);
            const int c  = tid & 15;
            const int cp = (c & 8) | ((c & 7) ^ (m & 7));
            bf16x8 v8 = *(const bf16x8*)&Sh[m * 128 + cp * 8];
            const int nl = c * 8;
            const int h  = (bn & 7) * 2 + (nl >> 6);
            const int d  = nl & 63;
            const int t  = tloc + m;
            *(bf16x8*)&ws[(size_t)which * WS_STRIDE
                          + ((size_t)(bi * NH + h) * T_SEQ + t) * D_HEAD + d] = v8;
        }
    } else {
#pragma unroll
        for (int i = 0; i < 4; i++) {
#pragma unroll
            for (int j = 0; j < 4; j++) {
                const int n = wn * 64 + j * 16 + l15;
#pragma unroll
                for (int p = 0; p < 2; p++) {
                    const int m0 = wm * 64 + i * 16 + l4 * 4 + 2 * p;
                    const int ch = m0 >> 3;
                    const int cp = (ch & 8) | ((ch & 7) ^ (n & 7));
                    *(unsigned*)&Sh[n * 128 + cp * 8 + (m0 & 7)] =
                        pack_bf16(acc[i][j][2 * p] + bv[j], acc[i][j][2 * p + 1] + bv[j]);
                }
            }
        }
        __syncthreads();
        bf16* vt = ws + 2 * (size_t)WS_STRIDE;
#pragma unroll
        for (int it = 0; it < 8; it++) {
            const int n  = it * 16 + (tid >> 4);
            const int mc = tid & 15;
            const int cp = (mc & 8) | ((mc & 7) ^ (n & 7));
            bf16x8 v8 = *(const bf16x8*)&Sh[n * 128 + cp * 8];
            const int h  = (bn & 7) * 2 + (n >> 6);
            const int d  = n & 63;
            const int t  = tloc + mc * 8;
            *(bf16x8*)&vt[((size_t)(bi * NH + h) * D_HEAD + d) * T_SEQ + t] = v8;
        }
    }
}

// ---------------------------------------------------------------------------
// Kernel 1 fallback (ws too small): register-convert GEMM, scalar epilogue.
// ---------------------------------------------------------------------------
__global__ __launch_bounds__(256) void qkv_gemm(
    const float* __restrict__ x, const float* __restrict__ W,
    const float* __restrict__ bias, bf16* __restrict__ ws,
    float* __restrict__ out)
{
    __shared__ bf16 As[128 * 40];
    __shared__ bf16 Bs[128 * 40];

    const int tid  = threadIdx.x;
    const int lane = tid & 63;
    const int w    = tid >> 6;
    const int wm   = w >> 1, wn = w & 1;
    const int l15  = lane & 15, l4 = lane >> 4;
    const int bm   = blockIdx.x / 24, bn = blockIdx.x % 24;

    {
        float4 z = {0.f, 0.f, 0.f, 0.f};
        for (int i = blockIdx.x * 256 + tid; i < OUT_F4; i += 768 * 256)
            ((float4*)out)[i] = z;
    }

    const int srow = tid >> 1;
    const int scol = (tid & 1) * 16;
    const float* xg = x + (size_t)(bm * 128 + srow) * 1024 + scol;
    const float* wg = W + (size_t)(bn * 128 + srow) * 1024 + scol;
    bf16* asw = &As[srow * 40 + scol];
    bf16* bsw = &Bs[srow * 40 + scol];

    f32x4 acc[4][4];
#pragma unroll
    for (int i = 0; i < 4; i++)
#pragma unroll
        for (int j = 0; j < 4; j++) acc[i][j] = (f32x4){0.f, 0.f, 0.f, 0.f};

    float bv[4];
#pragma unroll
    for (int j = 0; j < 4; j++) bv[j] = bias[bn * 128 + wn * 64 + j * 16 + l15];

    for (int kk = 0; kk < 32; ++kk) {
        const float* xp = xg + kk * 32;
        const float* wp = wg + kk * 32;
        float4 a0 = *(const float4*)(xp + 0);
        float4 a1 = *(const float4*)(xp + 4);
        float4 a2 = *(const float4*)(xp + 8);
        float4 a3 = *(const float4*)(xp + 12);
        float4 b0 = *(const float4*)(wp + 0);
        float4 b1 = *(const float4*)(wp + 4);
        float4 b2 = *(const float4*)(wp + 8);
        float4 b3 = *(const float4*)(wp + 12);

        __syncthreads();
        *(bf16x8*)(asw + 0) = cvt8(a0, a1);
        *(bf16x8*)(asw + 8) = cvt8(a2, a3);
        *(bf16x8*)(bsw + 0) = cvt8(b0, b1);
        *(bf16x8*)(bsw + 8) = cvt8(b2, b3);
        __syncthreads();

        bf16x8 aF[4], bF[4];
#pragma unroll
        for (int s = 0; s < 4; s++) {
            aF[s] = *(const bf16x8*)&As[(wm * 64 + s * 16 + l15) * 40 + l4 * 8];
            bF[s] = *(const bf16x8*)&Bs[(wn * 64 + s * 16 + l15) * 40 + l4 * 8];
        }
#pragma unroll
        for (int i = 0; i < 4; i++)
#pragma unroll
            for (int j = 0; j < 4; j++)
                acc[i][j] = __builtin_amdgcn_mfma_f32_16x16x32_bf16(
                    aF[i], bF[j], acc[i][j], 0, 0, 0);
    }

#pragma unroll
    for (int i = 0; i < 4; i++) {
#pragma unroll
        for (int j = 0; j < 4; j++) {
            const int n     = bn * 128 + wn * 64 + j * 16 + l15;
            const int which = n >> 10;
            const int cc    = n & 1023;
            const int h     = cc >> 6, d = cc & 63;
            const float qs  = (which == 0) ? 0.125f : 1.0f;
#pragma unroll
            for (int r = 0; r < 4; r++) {
                const int m  = bm * 128 + wm * 64 + i * 16 + l4 * 4 + r;
                const int bi = m >> 11, t = m & 2047;
                const int bh = bi * NH + h;
                const float v = (acc[i][j][r] + bv[j]) * qs;
                size_t idx;
                if (which == 2)
                    idx = 2 * (size_t)WS_STRIDE + ((size_t)bh * D_HEAD + d) * T_SEQ + t;
                else
                    idx = (size_t)which * WS_STRIDE + ((size_t)bh * T_SEQ + t) * D_HEAD + d;
                ws[idx] = (__bf16)v;
            }
        }
    }
}

// ---------------------------------------------------------------------------
// Kernel 2: causal ReLU attention v3.
// BM=128 q x BN=128 keys per step. K[128][64] and V^T[64][128] staged in
// XOR-swizzled LDS via global_load_lds (shared by all 4 waves -> 1/4 the L2
// traffic of direct loads). Permuted-K rows make S^T C-registers directly the
// PV A-fragments (no cross-lane transfer). Work list: per bh, the 136 (qt,jt)
// tiles flattened and chunked 4-per-block -> 1088 perfectly balanced blocks.
// blockIdx = chunk*32+bh keeps bh<->XCD affinity. O flushed by atomicAdd at
// qt boundaries (out pre-zeroed by cvt).
// ---------------------------------------------------------------------------
__global__ __launch_bounds__(256) void attn(
    const bf16* __restrict__ ws, float* __restrict__ out)
{
    __shared__ bf16 Ks[128 * 64];    // [key][d], chunk-XOR-swizzled (8 chunks)
    __shared__ bf16 Vts[64 * 128];   // [d][key], chunk-XOR-swizzled (16 chunks)

    const int tid  = threadIdx.x;
    const int lane = tid & 63;
    const int w    = tid >> 6;
    const int l15  = lane & 15, qd = lane >> 4;

    const int bh    = blockIdx.x & 31;   // XCD = blk&7 -> bh mod 8 affinity
    const int chunk = blockIdx.x >> 5;   // 0..33

    const bf16* qg = ws + (size_t)bh * (T_SEQ * D_HEAD);
    const bf16* kg = ws + WS_STRIDE + (size_t)bh * (T_SEQ * D_HEAD);
    const bf16* vt = ws + 2 * (size_t)WS_STRIDE + (size_t)bh * (D_HEAD * T_SEQ);
    const int b = bh >> 4, h = bh & 15;

    // decode first work item (triangular): item i -> (qt, jt), jt in [0,qt]
    int qt = 0, rem = chunk * 4;
    while (rem > qt) { rem -= qt + 1; qt++; }
    int jt = rem;

    // staging lane constants
    const int ksub  = lane >> 3;             // K: row-in-issue 0..7
    const int kcsrc = (lane & 7) ^ ksub;     // K: swizzled global chunk
    const int vsub  = lane >> 4;             // V: row-in-issue 0..3

    f32x4 o[2][4];
    bf16x8 qF[2][2];
    int cur_qt = -1;

    for (int s = 0; s < 4; ++s) {
        if (qt != cur_qt) {
            if (cur_qt >= 0) {   // flush O for previous q-tile
                const int qb = cur_qt * 128;
#pragma unroll
                for (int sm = 0; sm < 2; sm++)
#pragma unroll
                    for (int sd = 0; sd < 4; sd++) {
                        const int d = sd * 16 + l15;
#pragma unroll
                        for (int r = 0; r < 4; r++) {
                            const int t = qb + w * 32 + sm * 16 + qd * 4 + r;
                            unsafeAtomicAdd(
                                &out[((size_t)b * T_SEQ + t) * C_EMB + h * 64 + d],
                                o[sm][sd][r]);
                        }
                    }
            }
            cur_qt = qt;
#pragma unroll
            for (int sm = 0; sm < 2; sm++)
#pragma unroll
                for (int dk = 0; dk < 2; dk++)
                    qF[sm][dk] = *(const bf16x8*)(qg
                        + (qt * 128 + w * 32 + sm * 16 + l15) * 64 + dk * 32 + qd * 8);
#pragma unroll
            for (int sm = 0; sm < 2; sm++)
#pragma unroll
                for (int sd = 0; sd < 4; sd++) o[sm][sd] = (f32x4){0.f, 0.f, 0.f, 0.f};
        }

        __syncthreads();   // prev step's LDS fragment reads complete
        // ---- stage K tile [128][64]: 4 issues/wave, rows w*32+e*8.. ----
#pragma unroll
        for (int e = 0; e < 4; e++) {
            const int rl = w * 32 + e * 8 + ksub;
            gl_lds16(kg + (size_t)(jt * 128 + rl) * 64 + kcsrc * 8,
                     &Ks[(w * 32 + e * 8) * 64]);
        }
        // ---- stage V^T tile [64][128]: 4 issues/wave, rows w*16+e*4.. ----
#pragma unroll
        for (int e = 0; e < 4; e++) {
            const int rl    = w * 16 + e * 4 + vsub;
            const int vcsrc = (lane & 15) ^ (e * 4 + vsub);
            gl_lds16(vt + (size_t)rl * T_SEQ + jt * 128 + vcsrc * 8,
                     &Vts[(w * 16 + e * 4) * 128]);
        }
        __syncthreads();   // drains vmcnt -> staging visible

        // ---- QK (permuted rows) + mask + pack, per kn ----
        const bool need_mask = (jt == qt);
        unsigned PK[2][8][2];
#pragma unroll
        for (int kn = 0; kn < 8; kn++) {
            const int r7  = 4 * (kn & 1) + (l15 & 3);
            const int row = 32 * (kn >> 1) + 8 * (l15 >> 2) + r7;
            bf16x8 kf0 = *(const bf16x8*)&Ks[row * 64 + ((qd ^ r7) * 8)];
            bf16x8 kf1 = *(const bf16x8*)&Ks[row * 64 + (((4 + qd) ^ r7) * 8)];
            f32x4 s0 = {0.f, 0.f, 0.f, 0.f}, s1 = {0.f, 0.f, 0.f, 0.f};
            s0 = __builtin_amdgcn_mfma_f32_16x16x32_bf16(kf0, qF[0][0], s0, 0, 0, 0);
            s0 = __builtin_amdgcn_mfma_f32_16x16x32_bf16(kf1, qF[0][1], s0, 0, 0, 0);
            s1 = __builtin_amdgcn_mfma_f32_16x16x32_bf16(kf0, qF[1][0], s1, 0, 0, 0);
            s1 = __builtin_amdgcn_mfma_f32_16x16x32_bf16(kf1, qF[1][1], s1, 0, 0, 0);
            const int keyb = 32 * (kn >> 1) + 8 * qd + 4 * (kn & 1);
#pragma unroll
            for (int sm = 0; sm < 2; sm++) {
                const f32x4 sv = sm ? s1 : s0;
                const int ql = w * 32 + sm * 16 + l15;
                float v[4];
#pragma unroll
                for (int r = 0; r < 4; r++) {
                    float val = fmaxf(sv[r], 0.f);
                    if (need_mask && ql < keyb + r) val = 0.f;
                    v[r] = val;
                }
                PK[sm][kn][0] = pack_bf16(v[0], v[1]);
                PK[sm][kn][1] = pack_bf16(v[2], v[3]);
            }
        }

        // ---- PV: pF direct from this lane's PK dwords; vF from LDS ----
#pragma unroll
        for (int kk = 0; kk < 4; kk++) {
            bf16x8 pF[2];
#pragma unroll
            for (int sm = 0; sm < 2; sm++) {
                union { unsigned dw[4]; bf16x8 v; } u;
                u.dw[0] = PK[sm][2 * kk + 0][0];
                u.dw[1] = PK[sm][2 * kk + 0][1];
                u.dw[2] = PK[sm][2 * kk + 1][0];
                u.dw[3] = PK[sm][2 * kk + 1][1];
                pF[sm] = u.v;
            }
#pragma unroll
            for (int sd = 0; sd < 4; sd++) {
                bf16x8 vf = *(const bf16x8*)&Vts[(sd * 16 + l15) * 128
                                                 + (((kk * 4 + qd) ^ l15) * 8)];
                o[0][sd] = __builtin_amdgcn_mfma_f32_16x16x32_bf16(pF[0], vf, o[0][sd], 0, 0, 0);
                o[1][sd] = __builtin_amdgcn_mfma_f32_16x16x32_bf16(pF[1], vf, o[1][sd], 0, 0, 0);
            }
        }

        // advance work item
        jt++;
        if (jt > qt) { jt = 0; qt++; }
    }

    // final flush
    {
        const int qb = cur_qt * 128;
#pragma unroll
        for (int sm = 0; sm < 2; sm++)
#pragma unroll
            for (int sd = 0; sd < 4; sd++) {
                const int d = sd * 16 + l15;
#pragma unroll
                for (int r = 0; r < 4; r++) {
                    const int t = qb + w * 32 + sm * 16 + qd * 4 + r;
                    unsafeAtomicAdd(&out[((size_t)b * T_SEQ + t) * C_EMB + h * 64 + d],
                                    o[sm][sd][r]);
                }
            }
    }
}

extern "C" void kernel_launch(void* const* d_in, const int* in_sizes, int n_in,
                              void* d_out, int out_size, void* d_ws, size_t ws_size,
                              hipStream_t stream) {
    const float* x    = (const float*)d_in[0];
    const float* W    = (const float*)d_in[1];
    const float* bias = (const float*)d_in[2];
    float* out        = (float*)d_out;
    bf16*  ws         = (bf16*)d_ws;

    if (ws_size >= WS_NEEDED) {
        bf16* xb = ws + 3 * (size_t)WS_STRIDE;
        bf16* wb = xb + XN;
        cvt_bf16<<<dim3(CVT_GRID), dim3(256), 0, stream>>>(x, W, xb, wb, out);
        qkv_gemm2<<<dim3(768), dim3(256), 0, stream>>>(xb, wb, bias, ws);
    } else {
        qkv_gemm<<<dim3(768), dim3(256), 0, stream>>>(x, W, bias, ws, out);
    }
    attn<<<dim3(1088), dim3(256), 0, stream>>>(ws, out);
}

// Round 8
// 158.222 us; speedup vs baseline: 1.2432x; 1.0775x over previous
//
#include <hip/hip_runtime.h>

typedef __bf16 bf16;
typedef __bf16 bf16x8 __attribute__((ext_vector_type(8)));
typedef float  f32x4  __attribute__((ext_vector_type(4)));

#define T_SEQ   2048
#define D_HEAD  64
#define NH      16
#define BH      32
#define C_EMB   1024
#define WS_STRIDE (BH * T_SEQ * D_HEAD)   // 4,194,304 elems per plane
#define XN (4096 * 1024)
#define WN (3072 * 1024)
#define WS_NEEDED ((size_t)(3 * WS_STRIDE + XN + WN) * 2)
#define CVT_GRID 3584

__device__ __forceinline__ bf16x8 cvt8(float4 a, float4 b) {
    bf16x8 r;
    r[0] = (__bf16)a.x; r[1] = (__bf16)a.y; r[2] = (__bf16)a.z; r[3] = (__bf16)a.w;
    r[4] = (__bf16)b.x; r[5] = (__bf16)b.y; r[6] = (__bf16)b.z; r[7] = (__bf16)b.w;
    return r;
}

__device__ __forceinline__ void gl_lds16(const bf16* g, bf16* l) {
    __builtin_amdgcn_global_load_lds(
        (const __attribute__((address_space(1))) unsigned int*)g,
        (__attribute__((address_space(3))) unsigned int*)l,
        16, 0, 0);
}

__device__ __forceinline__ unsigned pack_bf16(float a, float b) {
    union { __bf16 h[2]; unsigned u; } pk;
    pk.h[0] = (__bf16)a; pk.h[1] = (__bf16)b;
    return pk.u;
}

// ---------------------------------------------------------------------------
// Kernel 0: fp32 -> bf16 convert of x and W (out-zeroing no longer needed).
// ---------------------------------------------------------------------------
__global__ __launch_bounds__(256) void cvt_bf16(
    const float* __restrict__ x, const float* __restrict__ W,
    bf16* __restrict__ xb, bf16* __restrict__ wb)
{
    const int t = blockIdx.x * 256 + threadIdx.x;   // 917504 threads
    const float* src; bf16* dst; int base;
    if (t < XN / 8) { src = x; dst = xb; base = t * 8; }
    else           { src = W; dst = wb; base = (t - XN / 8) * 8; }
    float4 a = *(const float4*)(src + base);
    float4 b = *(const float4*)(src + base + 4);
    *(bf16x8*)(dst + base) = cvt8(a, b);
}

// ---------------------------------------------------------------------------
// Kernel 1: qkv = xb @ wb^T + b. BK=64, XOR-swizzled LDS staging via
// global_load_lds w=16. Epilogue: LDS-transpose -> coalesced b128 stores.
// q plane pre-scaled by 0.125; v plane written transposed vt[bh][d][t].
// ---------------------------------------------------------------------------
__global__ __launch_bounds__(256) void qkv_gemm2(
    const bf16* __restrict__ xb, const bf16* __restrict__ wb,
    const float* __restrict__ bias, bf16* __restrict__ ws)
{
    __shared__ bf16 Sh[2 * 128 * 64];     // main loop: As|Bs; epilogue: 128x128
    bf16* As = Sh;
    bf16* Bs = Sh + 128 * 64;

    const int tid  = threadIdx.x;
    const int lane = tid & 63;
    const int w    = tid >> 6;
    const int wm   = w >> 1, wn = w & 1;
    const int l15  = lane & 15, l4 = lane >> 4;
    const int bm   = blockIdx.x / 24, bn = blockIdx.x % 24;

    const int srow  = lane >> 3;            // 0..7
    const int csrc  = (lane & 7) ^ srow;    // XOR-swizzled global chunk
    const bf16* ag = xb + (size_t)(bm * 128 + w * 32 + srow) * 1024 + csrc * 8;
    const bf16* bg = wb + (size_t)(bn * 128 + w * 32 + srow) * 1024 + csrc * 8;
    bf16* al = &As[w * 2048];
    bf16* bl = &Bs[w * 2048];

    f32x4 acc[4][4];
#pragma unroll
    for (int i = 0; i < 4; i++)
#pragma unroll
        for (int j = 0; j < 4; j++) acc[i][j] = (f32x4){0.f, 0.f, 0.f, 0.f};

    float bv[4];
#pragma unroll
    for (int j = 0; j < 4; j++) bv[j] = bias[bn * 128 + wn * 64 + j * 16 + l15];

    for (int kk = 0; kk < 16; ++kk) {
        __syncthreads();   // prev iteration's fragment reads complete
#pragma unroll
        for (int e = 0; e < 4; e++) {
            gl_lds16(ag + kk * 64 + e * 8 * 1024, al + e * 512);
            gl_lds16(bg + kk * 64 + e * 8 * 1024, bl + e * 512);
        }
        __syncthreads();   // drains vmcnt -> staging visible

        bf16x8 aF[4][2], bF[4][2];
#pragma unroll
        for (int s = 0; s < 4; s++) {
#pragma unroll
            for (int dk = 0; dk < 2; dk++) {
                const int ra = wm * 64 + s * 16 + l15;
                const int rb = wn * 64 + s * 16 + l15;
                aF[s][dk] = *(const bf16x8*)&As[ra * 64 + (((dk * 4 + l4) ^ (ra & 7)) * 8)];
                bF[s][dk] = *(const bf16x8*)&Bs[rb * 64 + (((dk * 4 + l4) ^ (rb & 7)) * 8)];
            }
        }
#pragma unroll
        for (int dk = 0; dk < 2; dk++)
#pragma unroll
            for (int i = 0; i < 4; i++)
#pragma unroll
                for (int j = 0; j < 4; j++)
                    acc[i][j] = __builtin_amdgcn_mfma_f32_16x16x32_bf16(
                        aF[i][dk], bF[j][dk], acc[i][j], 0, 0, 0);
    }

    // ---- epilogue: +bias (+0.125 scale for q); LDS transpose -> b128 stores
    __syncthreads();                       // all fragment reads done
    const int which = bn >> 3;             // 0=q, 1=k, 2=v (block-uniform)
    const int bi    = bm >> 4;             // batch (block-uniform)
    const int tloc  = (bm & 15) * 128;     // t-offset within this batch
    const float qs  = (which == 0) ? 0.125f : 1.0f;

    if (which < 2) {
#pragma unroll
        for (int i = 0; i < 4; i++) {
#pragma unroll
            for (int j = 0; j < 4; j++) {
                const int n = wn * 64 + j * 16 + l15;
                const int c = n >> 3;
#pragma unroll
                for (int r = 0; r < 4; r++) {
                    const int m  = wm * 64 + i * 16 + l4 * 4 + r;
                    const int cp = (c & 8) | ((c & 7) ^ (m & 7));
                    Sh[m * 128 + cp * 8 + (n & 7)] = (__bf16)((acc[i][j][r] + bv[j]) * qs);
                }
            }
        }
        __syncthreads();
#pragma unroll
        for (int it = 0; it < 8; it++) {
            const int m  = it * 16 + (tid >> 4);
            const int c  = tid & 15;
            const int cp = (c & 8) | ((c & 7) ^ (m & 7));
            bf16x8 v8 = *(const bf16x8*)&Sh[m * 128 + cp * 8];
            const int nl = c * 8;
            const int h  = (bn & 7) * 2 + (nl >> 6);
            const int d  = nl & 63;
            const int t  = tloc + m;
            *(bf16x8*)&ws[(size_t)which * WS_STRIDE
                          + ((size_t)(bi * NH + h) * T_SEQ + t) * D_HEAD + d] = v8;
        }
    } else {
#pragma unroll
        for (int i = 0; i < 4; i++) {
#pragma unroll
            for (int j = 0; j < 4; j++) {
                const int n = wn * 64 + j * 16 + l15;
#pragma unroll
                for (int p = 0; p < 2; p++) {
                    const int m0 = wm * 64 + i * 16 + l4 * 4 + 2 * p;
                    const int ch = m0 >> 3;
                    const int cp = (ch & 8) | ((ch & 7) ^ (n & 7));
                    *(unsigned*)&Sh[n * 128 + cp * 8 + (m0 & 7)] =
                        pack_bf16(acc[i][j][2 * p] + bv[j], acc[i][j][2 * p + 1] + bv[j]);
                }
            }
        }
        __syncthreads();
        bf16* vt = ws + 2 * (size_t)WS_STRIDE;
#pragma unroll
        for (int it = 0; it < 8; it++) {
            const int n  = it * 16 + (tid >> 4);
            const int mc = tid & 15;
            const int cp = (mc & 8) | ((mc & 7) ^ (n & 7));
            bf16x8 v8 = *(const bf16x8*)&Sh[n * 128 + cp * 8];
            const int h  = (bn & 7) * 2 + (n >> 6);
            const int d  = n & 63;
            const int t  = tloc + mc * 8;
            *(bf16x8*)&vt[((size_t)(bi * NH + h) * D_HEAD + d) * T_SEQ + t] = v8;
        }
    }
}

// ---------------------------------------------------------------------------
// Kernel 1 fallback (ws too small): register-convert GEMM, scalar epilogue.
// ---------------------------------------------------------------------------
__global__ __launch_bounds__(256) void qkv_gemm(
    const float* __restrict__ x, const float* __restrict__ W,
    const float* __restrict__ bias, bf16* __restrict__ ws)
{
    __shared__ bf16 As[128 * 40];
    __shared__ bf16 Bs[128 * 40];

    const int tid  = threadIdx.x;
    const int lane = tid & 63;
    const int w    = tid >> 6;
    const int wm   = w >> 1, wn = w & 1;
    const int l15  = lane & 15, l4 = lane >> 4;
    const int bm   = blockIdx.x / 24, bn = blockIdx.x % 24;

    const int srow = tid >> 1;
    const int scol = (tid & 1) * 16;
    const float* xg = x + (size_t)(bm * 128 + srow) * 1024 + scol;
    const float* wg = W + (size_t)(bn * 128 + srow) * 1024 + scol;
    bf16* asw = &As[srow * 40 + scol];
    bf16* bsw = &Bs[srow * 40 + scol];

    f32x4 acc[4][4];
#pragma unroll
    for (int i = 0; i < 4; i++)
#pragma unroll
        for (int j = 0; j < 4; j++) acc[i][j] = (f32x4){0.f, 0.f, 0.f, 0.f};

    float bv[4];
#pragma unroll
    for (int j = 0; j < 4; j++) bv[j] = bias[bn * 128 + wn * 64 + j * 16 + l15];

    for (int kk = 0; kk < 32; ++kk) {
        const float* xp = xg + kk * 32;
        const float* wp = wg + kk * 32;
        float4 a0 = *(const float4*)(xp + 0);
        float4 a1 = *(const float4*)(xp + 4);
        float4 a2 = *(const float4*)(xp + 8);
        float4 a3 = *(const float4*)(xp + 12);
        float4 b0 = *(const float4*)(wp + 0);
        float4 b1 = *(const float4*)(wp + 4);
        float4 b2 = *(const float4*)(wp + 8);
        float4 b3 = *(const float4*)(wp + 12);

        __syncthreads();
        *(bf16x8*)(asw + 0) = cvt8(a0, a1);
        *(bf16x8*)(asw + 8) = cvt8(a2, a3);
        *(bf16x8*)(bsw + 0) = cvt8(b0, b1);
        *(bf16x8*)(bsw + 8) = cvt8(b2, b3);
        __syncthreads();

        bf16x8 aF[4], bF[4];
#pragma unroll
        for (int s = 0; s < 4; s++) {
            aF[s] = *(const bf16x8*)&As[(wm * 64 + s * 16 + l15) * 40 + l4 * 8];
            bF[s] = *(const bf16x8*)&Bs[(wn * 64 + s * 16 + l15) * 40 + l4 * 8];
        }
#pragma unroll
        for (int i = 0; i < 4; i++)
#pragma unroll
            for (int j = 0; j < 4; j++)
                acc[i][j] = __builtin_amdgcn_mfma_f32_16x16x32_bf16(
                    aF[i], bF[j], acc[i][j], 0, 0, 0);
    }

#pragma unroll
    for (int i = 0; i < 4; i++) {
#pragma unroll
        for (int j = 0; j < 4; j++) {
            const int n     = bn * 128 + wn * 64 + j * 16 + l15;
            const int which = n >> 10;
            const int cc    = n & 1023;
            const int h     = cc >> 6, d = cc & 63;
            const float qs  = (which == 0) ? 0.125f : 1.0f;
#pragma unroll
            for (int r = 0; r < 4; r++) {
                const int m  = bm * 128 + wm * 64 + i * 16 + l4 * 4 + r;
                const int bi = m >> 11, t = m & 2047;
                const int bh = bi * NH + h;
                const float v = (acc[i][j][r] + bv[j]) * qs;
                size_t idx;
                if (which == 2)
                    idx = 2 * (size_t)WS_STRIDE + ((size_t)bh * D_HEAD + d) * T_SEQ + t;
                else
                    idx = (size_t)which * WS_STRIDE + ((size_t)bh * T_SEQ + t) * D_HEAD + d;
                ws[idx] = (__bf16)v;
            }
        }
    }
}

// ---------------------------------------------------------------------------
// Kernel 2: causal ReLU attention v4 — NO ATOMICS.
// 512 blocks x 128 threads (2 waves). Block = (bh, p); processes q-tiles
// qt'=p and qt'=31-p (BM=64, BN=128). nj(qt')=(qt'>>1)+1, pair sums to 17
// steps exactly -> perfect balance, exclusive q-row ownership -> plain fp32
// stores (no out pre-zero). K[128][64] + V^T[64][128] staged in XOR-swizzled
// LDS via global_load_lds; permuted-K rows keep P in-lane for PV.
// 2 blocks/CU co-resident (32 KB LDS) overlap barrier drains.
// ---------------------------------------------------------------------------
__global__ __launch_bounds__(128) void attn(
    const bf16* __restrict__ ws, float* __restrict__ out)
{
    __shared__ bf16 Ks[128 * 64];    // [key][d], 8-chunk XOR swizzle
    __shared__ bf16 Vts[64 * 128];   // [d][key], 16-chunk XOR swizzle

    const int tid  = threadIdx.x;
    const int lane = tid & 63;
    const int w    = tid >> 6;           // 0..1
    const int l15  = lane & 15, qd = lane >> 4;

    const int bh = blockIdx.x & 31;      // XCD = blk&7 -> bh mod 8 affinity
    const int p  = blockIdx.x >> 5;      // 0..15

    const bf16* qg = ws + (size_t)bh * (T_SEQ * D_HEAD);
    const bf16* kg = ws + WS_STRIDE + (size_t)bh * (T_SEQ * D_HEAD);
    const bf16* vt = ws + 2 * (size_t)WS_STRIDE + (size_t)bh * (D_HEAD * T_SEQ);
    const int b = bh >> 4, h = bh & 15;

    // staging lane constants
    const int ksub = lane >> 3;          // K: row-in-issue 0..7
    const int kc   = lane & 7;           // K: stored chunk
    const int vsub = qd;                 // V: row-in-issue 0..3
    const int vc   = l15;                // V: stored chunk

#pragma unroll
    for (int ti = 0; ti < 2; ++ti) {
        const int qt = ti ? (31 - p) : p;
        const int nj = (qt >> 1) + 1;
        const int qb = qt * 64;

        // Q fragments (pre-scaled by 1/8)
        bf16x8 qF[2][2];
#pragma unroll
        for (int sm = 0; sm < 2; sm++)
#pragma unroll
            for (int dk = 0; dk < 2; dk++)
                qF[sm][dk] = *(const bf16x8*)(qg
                    + (qb + w * 32 + sm * 16 + l15) * 64 + dk * 32 + qd * 8);

        f32x4 o[2][4];
#pragma unroll
        for (int sm = 0; sm < 2; sm++)
#pragma unroll
            for (int sd = 0; sd < 4; sd++) o[sm][sd] = (f32x4){0.f, 0.f, 0.f, 0.f};

        for (int jt = 0; jt < nj; ++jt) {
            __syncthreads();   // prev step's LDS fragment reads complete
            // ---- stage K tile [128][64]: 8 issues/wave (8 rows each) ----
#pragma unroll
            for (int e = 0; e < 8; e++) {
                const int rb = w * 64 + e * 8;
                gl_lds16(kg + (size_t)(jt * 128 + rb + ksub) * 64 + ((kc ^ ksub) * 8),
                         &Ks[rb * 64]);
            }
            // ---- stage V^T tile [64][128]: 8 issues/wave (4 rows each) ----
#pragma unroll
            for (int e = 0; e < 8; e++) {
                const int rb = w * 32 + e * 4;
                const int sw = (rb & 12) + vsub;   // (row & 15) for this lane
                gl_lds16(vt + (size_t)(rb + vsub) * T_SEQ + jt * 128 + ((vc ^ sw) * 8),
                         &Vts[rb * 128]);
            }
            __syncthreads();   // drains vmcnt -> staging visible

            // ---- QK (permuted rows) + mask + pack, per kn ----
            const bool need_mask = (jt == nj - 1);
            unsigned PK[2][8][2];
#pragma unroll
            for (int kn = 0; kn < 8; kn++) {
                const int r7  = 4 * (kn & 1) + (l15 & 3);
                const int row = 32 * (kn >> 1) + 8 * (l15 >> 2) + r7;
                bf16x8 kf0 = *(const bf16x8*)&Ks[row * 64 + ((qd ^ r7) * 8)];
                bf16x8 kf1 = *(const bf16x8*)&Ks[row * 64 + (((4 + qd) ^ r7) * 8)];
                f32x4 s0 = {0.f, 0.f, 0.f, 0.f}, s1 = {0.f, 0.f, 0.f, 0.f};
                s0 = __builtin_amdgcn_mfma_f32_16x16x32_bf16(kf0, qF[0][0], s0, 0, 0, 0);
                s0 = __builtin_amdgcn_mfma_f32_16x16x32_bf16(kf1, qF[0][1], s0, 0, 0, 0);
                s1 = __builtin_amdgcn_mfma_f32_16x16x32_bf16(kf0, qF[1][0], s1, 0, 0, 0);
                s1 = __builtin_amdgcn_mfma_f32_16x16x32_bf16(kf1, qF[1][1], s1, 0, 0, 0);
                const int keyb = jt * 128 + 32 * (kn >> 1) + 8 * qd + 4 * (kn & 1);
#pragma unroll
                for (int sm = 0; sm < 2; sm++) {
                    const f32x4 sv = sm ? s1 : s0;
                    const int q = qb + w * 32 + sm * 16 + l15;
                    float v[4];
#pragma unroll
                    for (int r = 0; r < 4; r++) {
                        float val = fmaxf(sv[r], 0.f);
                        if (need_mask && q < keyb + r) val = 0.f;
                        v[r] = val;
                    }
                    PK[sm][kn][0] = pack_bf16(v[0], v[1]);
                    PK[sm][kn][1] = pack_bf16(v[2], v[3]);
                }
            }

            // ---- PV: pF direct from this lane's PK dwords; vF from LDS ----
#pragma unroll
            for (int kk = 0; kk < 4; kk++) {
                bf16x8 pF[2];
#pragma unroll
                for (int sm = 0; sm < 2; sm++) {
                    union { unsigned dw[4]; bf16x8 v; } u;
                    u.dw[0] = PK[sm][2 * kk + 0][0];
                    u.dw[1] = PK[sm][2 * kk + 0][1];
                    u.dw[2] = PK[sm][2 * kk + 1][0];
                    u.dw[3] = PK[sm][2 * kk + 1][1];
                    pF[sm] = u.v;
                }
#pragma unroll
                for (int sd = 0; sd < 4; sd++) {
                    bf16x8 vf = *(const bf16x8*)&Vts[(sd * 16 + l15) * 128
                                                     + (((kk * 4 + qd) ^ l15) * 8)];
                    o[0][sd] = __builtin_amdgcn_mfma_f32_16x16x32_bf16(pF[0], vf, o[0][sd], 0, 0, 0);
                    o[1][sd] = __builtin_amdgcn_mfma_f32_16x16x32_bf16(pF[1], vf, o[1][sd], 0, 0, 0);
                }
            }
        }

        // ---- plain-store O (exclusive q-row ownership) ----
#pragma unroll
        for (int sm = 0; sm < 2; sm++)
#pragma unroll
            for (int sd = 0; sd < 4; sd++) {
                const int d = sd * 16 + l15;
#pragma unroll
                for (int r = 0; r < 4; r++) {
                    const int t = qb + w * 32 + sm * 16 + qd * 4 + r;
                    out[((size_t)b * T_SEQ + t) * C_EMB + h * 64 + d] = o[sm][sd][r];
                }
            }
    }
}

extern "C" void kernel_launch(void* const* d_in, const int* in_sizes, int n_in,
                              void* d_out, int out_size, void* d_ws, size_t ws_size,
                              hipStream_t stream) {
    const float* x    = (const float*)d_in[0];
    const float* W    = (const float*)d_in[1];
    const float* bias = (const float*)d_in[2];
    float* out        = (float*)d_out;
    bf16*  ws         = (bf16*)d_ws;

    if (ws_size >= WS_NEEDED) {
        bf16* xb = ws + 3 * (size_t)WS_STRIDE;
        bf16* wb = xb + XN;
        cvt_bf16<<<dim3(CVT_GRID), dim3(256), 0, stream>>>(x, W, xb, wb);
        qkv_gemm2<<<dim3(768), dim3(256), 0, stream>>>(xb, wb, bias, ws);
    } else {
        qkv_gemm<<<dim3(768), dim3(256), 0, stream>>>(x, W, bias, ws);
    }
    attn<<<dim3(512), dim3(128), 0, stream>>>(ws, out);
}

// Round 9
// 154.554 us; speedup vs baseline: 1.2727x; 1.0237x over previous
//
#include <hip/hip_runtime.h>

typedef __bf16 bf16;
typedef __bf16 bf16x8 __attribute__((ext_vector_type(8)));
typedef float  f32x4  __attribute__((ext_vector_type(4)));

#define T_SEQ   2048
#define D_HEAD  64
#define NH      16
#define BH      32
#define C_EMB   1024
#define WS_STRIDE (BH * T_SEQ * D_HEAD)   // 4,194,304 elems per plane
#define XN (4096 * 1024)
#define WN (3072 * 1024)
#define WS_NEEDED ((size_t)(3 * WS_STRIDE + XN + WN) * 2)
#define CVT_GRID 3584

__device__ __forceinline__ bf16x8 cvt8(float4 a, float4 b) {
    bf16x8 r;
    r[0] = (__bf16)a.x; r[1] = (__bf16)a.y; r[2] = (__bf16)a.z; r[3] = (__bf16)a.w;
    r[4] = (__bf16)b.x; r[5] = (__bf16)b.y; r[6] = (__bf16)b.z; r[7] = (__bf16)b.w;
    return r;
}

__device__ __forceinline__ void gl_lds16(const bf16* g, bf16* l) {
    __builtin_amdgcn_global_load_lds(
        (const __attribute__((address_space(1))) unsigned int*)g,
        (__attribute__((address_space(3))) unsigned int*)l,
        16, 0, 0);
}

__device__ __forceinline__ unsigned pack_bf16(float a, float b) {
    union { __bf16 h[2]; unsigned u; } pk;
    pk.h[0] = (__bf16)a; pk.h[1] = (__bf16)b;
    return pk.u;
}

// ---------------------------------------------------------------------------
// Kernel 0: fp32 -> bf16 convert of x and W.
// ---------------------------------------------------------------------------
__global__ __launch_bounds__(256) void cvt_bf16(
    const float* __restrict__ x, const float* __restrict__ W,
    bf16* __restrict__ xb, bf16* __restrict__ wb)
{
    const int t = blockIdx.x * 256 + threadIdx.x;   // 917504 threads
    const float* src; bf16* dst; int base;
    if (t < XN / 8) { src = x; dst = xb; base = t * 8; }
    else           { src = W; dst = wb; base = (t - XN / 8) * 8; }
    float4 a = *(const float4*)(src + base);
    float4 b = *(const float4*)(src + base + 4);
    *(bf16x8*)(dst + base) = cvt8(a, b);
}

// ---------------------------------------------------------------------------
// Kernel 1: qkv = xb @ wb^T + b. BK=64, XOR-swizzled LDS staging via
// global_load_lds w=16. Epilogue: LDS-transpose -> coalesced b128 stores.
// q plane pre-scaled by 0.125; v plane written transposed vt[bh][d][t].
// ---------------------------------------------------------------------------
__global__ __launch_bounds__(256) void qkv_gemm2(
    const bf16* __restrict__ xb, const bf16* __restrict__ wb,
    const float* __restrict__ bias, bf16* __restrict__ ws)
{
    __shared__ bf16 Sh[2 * 128 * 64];     // main loop: As|Bs; epilogue: 128x128
    bf16* As = Sh;
    bf16* Bs = Sh + 128 * 64;

    const int tid  = threadIdx.x;
    const int lane = tid & 63;
    const int w    = tid >> 6;
    const int wm   = w >> 1, wn = w & 1;
    const int l15  = lane & 15, l4 = lane >> 4;
    const int bm   = blockIdx.x / 24, bn = blockIdx.x % 24;

    const int srow  = lane >> 3;            // 0..7
    const int csrc  = (lane & 7) ^ srow;    // XOR-swizzled global chunk
    const bf16* ag = xb + (size_t)(bm * 128 + w * 32 + srow) * 1024 + csrc * 8;
    const bf16* bg = wb + (size_t)(bn * 128 + w * 32 + srow) * 1024 + csrc * 8;
    bf16* al = &As[w * 2048];
    bf16* bl = &Bs[w * 2048];

    f32x4 acc[4][4];
#pragma unroll
    for (int i = 0; i < 4; i++)
#pragma unroll
        for (int j = 0; j < 4; j++) acc[i][j] = (f32x4){0.f, 0.f, 0.f, 0.f};

    float bv[4];
#pragma unroll
    for (int j = 0; j < 4; j++) bv[j] = bias[bn * 128 + wn * 64 + j * 16 + l15];

    for (int kk = 0; kk < 16; ++kk) {
        __syncthreads();   // prev iteration's fragment reads complete
#pragma unroll
        for (int e = 0; e < 4; e++) {
            gl_lds16(ag + kk * 64 + e * 8 * 1024, al + e * 512);
            gl_lds16(bg + kk * 64 + e * 8 * 1024, bl + e * 512);
        }
        __syncthreads();   // drains vmcnt -> staging visible

        bf16x8 aF[4][2], bF[4][2];
#pragma unroll
        for (int s = 0; s < 4; s++) {
#pragma unroll
            for (int dk = 0; dk < 2; dk++) {
                const int ra = wm * 64 + s * 16 + l15;
                const int rb = wn * 64 + s * 16 + l15;
                aF[s][dk] = *(const bf16x8*)&As[ra * 64 + (((dk * 4 + l4) ^ (ra & 7)) * 8)];
                bF[s][dk] = *(const bf16x8*)&Bs[rb * 64 + (((dk * 4 + l4) ^ (rb & 7)) * 8)];
            }
        }
#pragma unroll
        for (int dk = 0; dk < 2; dk++)
#pragma unroll
            for (int i = 0; i < 4; i++)
#pragma unroll
                for (int j = 0; j < 4; j++)
                    acc[i][j] = __builtin_amdgcn_mfma_f32_16x16x32_bf16(
                        aF[i][dk], bF[j][dk], acc[i][j], 0, 0, 0);
    }

    // ---- epilogue: +bias (+0.125 scale for q); LDS transpose -> b128 stores
    __syncthreads();                       // all fragment reads done
    const int which = bn >> 3;             // 0=q, 1=k, 2=v (block-uniform)
    const int bi    = bm >> 4;             // batch (block-uniform)
    const int tloc  = (bm & 15) * 128;     // t-offset within this batch
    const float qs  = (which == 0) ? 0.125f : 1.0f;

    if (which < 2) {
#pragma unroll
        for (int i = 0; i < 4; i++) {
#pragma unroll
            for (int j = 0; j < 4; j++) {
                const int n = wn * 64 + j * 16 + l15;
                const int c = n >> 3;
#pragma unroll
                for (int r = 0; r < 4; r++) {
                    const int m  = wm * 64 + i * 16 + l4 * 4 + r;
                    const int cp = (c & 8) | ((c & 7) ^ (m & 7));
                    Sh[m * 128 + cp * 8 + (n & 7)] = (__bf16)((acc[i][j][r] + bv[j]) * qs);
                }
            }
        }
        __syncthreads();
#pragma unroll
        for (int it = 0; it < 8; it++) {
            const int m  = it * 16 + (tid >> 4);
            const int c  = tid & 15;
            const int cp = (c & 8) | ((c & 7) ^ (m & 7));
            bf16x8 v8 = *(const bf16x8*)&Sh[m * 128 + cp * 8];
            const int nl = c * 8;
            const int h  = (bn & 7) * 2 + (nl >> 6);
            const int d  = nl & 63;
            const int t  = tloc + m;
            *(bf16x8*)&ws[(size_t)which * WS_STRIDE
                          + ((size_t)(bi * NH + h) * T_SEQ + t) * D_HEAD + d] = v8;
        }
    } else {
#pragma unroll
        for (int i = 0; i < 4; i++) {
#pragma unroll
            for (int j = 0; j < 4; j++) {
                const int n = wn * 64 + j * 16 + l15;
#pragma unroll
                for (int p = 0; p < 2; p++) {
                    const int m0 = wm * 64 + i * 16 + l4 * 4 + 2 * p;
                    const int ch = m0 >> 3;
                    const int cp = (ch & 8) | ((ch & 7) ^ (n & 7));
                    *(unsigned*)&Sh[n * 128 + cp * 8 + (m0 & 7)] =
                        pack_bf16(acc[i][j][2 * p] + bv[j], acc[i][j][2 * p + 1] + bv[j]);
                }
            }
        }
        __syncthreads();
        bf16* vt = ws + 2 * (size_t)WS_STRIDE;
#pragma unroll
        for (int it = 0; it < 8; it++) {
            const int n  = it * 16 + (tid >> 4);
            const int mc = tid & 15;
            const int cp = (mc & 8) | ((mc & 7) ^ (n & 7));
            bf16x8 v8 = *(const bf16x8*)&Sh[n * 128 + cp * 8];
            const int h  = (bn & 7) * 2 + (n >> 6);
            const int d  = n & 63;
            const int t  = tloc + mc * 8;
            *(bf16x8*)&vt[((size_t)(bi * NH + h) * D_HEAD + d) * T_SEQ + t] = v8;
        }
    }
}

// ---------------------------------------------------------------------------
// Kernel 1 fallback (ws too small): register-convert GEMM, scalar epilogue.
// ---------------------------------------------------------------------------
__global__ __launch_bounds__(256) void qkv_gemm(
    const float* __restrict__ x, const float* __restrict__ W,
    const float* __restrict__ bias, bf16* __restrict__ ws)
{
    __shared__ bf16 As[128 * 40];
    __shared__ bf16 Bs[128 * 40];

    const int tid  = threadIdx.x;
    const int lane = tid & 63;
    const int w    = tid >> 6;
    const int wm   = w >> 1, wn = w & 1;
    const int l15  = lane & 15, l4 = lane >> 4;
    const int bm   = blockIdx.x / 24, bn = blockIdx.x % 24;

    const int srow = tid >> 1;
    const int scol = (tid & 1) * 16;
    const float* xg = x + (size_t)(bm * 128 + srow) * 1024 + scol;
    const float* wg = W + (size_t)(bn * 128 + srow) * 1024 + scol;
    bf16* asw = &As[srow * 40 + scol];
    bf16* bsw = &Bs[srow * 40 + scol];

    f32x4 acc[4][4];
#pragma unroll
    for (int i = 0; i < 4; i++)
#pragma unroll
        for (int j = 0; j < 4; j++) acc[i][j] = (f32x4){0.f, 0.f, 0.f, 0.f};

    float bv[4];
#pragma unroll
    for (int j = 0; j < 4; j++) bv[j] = bias[bn * 128 + wn * 64 + j * 16 + l15];

    for (int kk = 0; kk < 32; ++kk) {
        const float* xp = xg + kk * 32;
        const float* wp = wg + kk * 32;
        float4 a0 = *(const float4*)(xp + 0);
        float4 a1 = *(const float4*)(xp + 4);
        float4 a2 = *(const float4*)(xp + 8);
        float4 a3 = *(const float4*)(xp + 12);
        float4 b0 = *(const float4*)(wp + 0);
        float4 b1 = *(const float4*)(wp + 4);
        float4 b2 = *(const float4*)(wp + 8);
        float4 b3 = *(const float4*)(wp + 12);

        __syncthreads();
        *(bf16x8*)(asw + 0) = cvt8(a0, a1);
        *(bf16x8*)(asw + 8) = cvt8(a2, a3);
        *(bf16x8*)(bsw + 0) = cvt8(b0, b1);
        *(bf16x8*)(bsw + 8) = cvt8(b2, b3);
        __syncthreads();

        bf16x8 aF[4], bF[4];
#pragma unroll
        for (int s = 0; s < 4; s++) {
            aF[s] = *(const bf16x8*)&As[(wm * 64 + s * 16 + l15) * 40 + l4 * 8];
            bF[s] = *(const bf16x8*)&Bs[(wn * 64 + s * 16 + l15) * 40 + l4 * 8];
        }
#pragma unroll
        for (int i = 0; i < 4; i++)
#pragma unroll
            for (int j = 0; j < 4; j++)
                acc[i][j] = __builtin_amdgcn_mfma_f32_16x16x32_bf16(
                    aF[i], bF[j], acc[i][j], 0, 0, 0);
    }

#pragma unroll
    for (int i = 0; i < 4; i++) {
#pragma unroll
        for (int j = 0; j < 4; j++) {
            const int n     = bn * 128 + wn * 64 + j * 16 + l15;
            const int which = n >> 10;
            const int cc    = n & 1023;
            const int h     = cc >> 6, d = cc & 63;
            const float qs  = (which == 0) ? 0.125f : 1.0f;
#pragma unroll
            for (int r = 0; r < 4; r++) {
                const int m  = bm * 128 + wm * 64 + i * 16 + l4 * 4 + r;
                const int bi = m >> 11, t = m & 2047;
                const int bh = bi * NH + h;
                const float v = (acc[i][j][r] + bv[j]) * qs;
                size_t idx;
                if (which == 2)
                    idx = 2 * (size_t)WS_STRIDE + ((size_t)bh * D_HEAD + d) * T_SEQ + t;
                else
                    idx = (size_t)which * WS_STRIDE + ((size_t)bh * T_SEQ + t) * D_HEAD + d;
                ws[idx] = (__bf16)v;
            }
        }
    }
}

// ---------------------------------------------------------------------------
// Kernel 2: causal ReLU attention v5 — no atomics, 2 waves/SIMD.
// 512 blocks x 256 threads (4 waves). Block u=blk>>5: qt = u<8 ? u : 23-u
// (each qt once per bh -> exclusive q-rows, plain stores). BM=128, BN=128,
// nj = qt+1 steps; round-robin CU pairing (u,u+8) sums to 17 steps.
// K[128][64] + V^T[64][128] in XOR-swizzled LDS via global_load_lds;
// permuted-K rows keep P in-lane for PV. 2 blocks/CU (32 KB LDS) ->
// 8 waves/CU = 2/SIMD for latency hiding + barrier overlap.
// ---------------------------------------------------------------------------
__global__ __launch_bounds__(256) void attn(
    const bf16* __restrict__ ws, float* __restrict__ out)
{
    __shared__ bf16 Ks[128 * 64];    // [key][d], 8-chunk XOR swizzle
    __shared__ bf16 Vts[64 * 128];   // [d][key], 16-chunk XOR swizzle

    const int tid  = threadIdx.x;
    const int lane = tid & 63;
    const int w    = tid >> 6;           // 0..3
    const int l15  = lane & 15, qd = lane >> 4;

    const int bh = blockIdx.x & 31;      // XCD = blk&7 -> bh mod 8 affinity
    const int u  = blockIdx.x >> 5;      // 0..15
    const int qt = (u < 8) ? u : (23 - u);
    const int nj = qt + 1;
    const int qb = qt * 128;

    const bf16* qg = ws + (size_t)bh * (T_SEQ * D_HEAD);
    const bf16* kg = ws + WS_STRIDE + (size_t)bh * (T_SEQ * D_HEAD);
    const bf16* vt = ws + 2 * (size_t)WS_STRIDE + (size_t)bh * (D_HEAD * T_SEQ);
    const int b = bh >> 4, h = bh & 15;

    // staging lane constants
    const int ksub = lane >> 3;          // K: row-in-issue 0..7
    const int kc   = lane & 7;           // K: stored chunk
    const int vsub = qd;                 // V: row-in-issue 0..3
    const int vc   = l15;                // V: stored chunk

    // Q fragments (pre-scaled by 1/8), live across whole loop
    bf16x8 qF[2][2];
#pragma unroll
    for (int sm = 0; sm < 2; sm++)
#pragma unroll
        for (int dk = 0; dk < 2; dk++)
            qF[sm][dk] = *(const bf16x8*)(qg
                + (qb + w * 32 + sm * 16 + l15) * 64 + dk * 32 + qd * 8);

    f32x4 o[2][4];
#pragma unroll
    for (int sm = 0; sm < 2; sm++)
#pragma unroll
        for (int sd = 0; sd < 4; sd++) o[sm][sd] = (f32x4){0.f, 0.f, 0.f, 0.f};

    for (int jt = 0; jt < nj; ++jt) {
        __syncthreads();   // prev step's LDS fragment reads complete
        // ---- stage K tile [128][64]: 4 issues/wave (8 rows each) ----
#pragma unroll
        for (int e = 0; e < 4; e++) {
            const int rb = w * 32 + e * 8;
            gl_lds16(kg + (size_t)(jt * 128 + rb + ksub) * 64 + ((kc ^ ksub) * 8),
                     &Ks[rb * 64]);
        }
        // ---- stage V^T tile [64][128]: 4 issues/wave (4 rows each) ----
#pragma unroll
        for (int e = 0; e < 4; e++) {
            const int rb = w * 16 + e * 4;
            const int sw = (rb & 12) + vsub;   // == (row & 15) for this lane
            gl_lds16(vt + (size_t)(rb + vsub) * T_SEQ + jt * 128 + ((vc ^ sw) * 8),
                     &Vts[rb * 128]);
        }
        __syncthreads();   // drains vmcnt -> staging visible

        // ---- QK (permuted rows) + mask + pack, per kn ----
        const bool need_mask = (jt == nj - 1);
        unsigned PK[2][8][2];
#pragma unroll
        for (int kn = 0; kn < 8; kn++) {
            const int r7  = 4 * (kn & 1) + (l15 & 3);
            const int row = 32 * (kn >> 1) + 8 * (l15 >> 2) + r7;
            bf16x8 kf0 = *(const bf16x8*)&Ks[row * 64 + ((qd ^ r7) * 8)];
            bf16x8 kf1 = *(const bf16x8*)&Ks[row * 64 + (((4 + qd) ^ r7) * 8)];
            f32x4 s0 = {0.f, 0.f, 0.f, 0.f}, s1 = {0.f, 0.f, 0.f, 0.f};
            s0 = __builtin_amdgcn_mfma_f32_16x16x32_bf16(kf0, qF[0][0], s0, 0, 0, 0);
            s0 = __builtin_amdgcn_mfma_f32_16x16x32_bf16(kf1, qF[0][1], s0, 0, 0, 0);
            s1 = __builtin_amdgcn_mfma_f32_16x16x32_bf16(kf0, qF[1][0], s1, 0, 0, 0);
            s1 = __builtin_amdgcn_mfma_f32_16x16x32_bf16(kf1, qF[1][1], s1, 0, 0, 0);
            const int keyb = jt * 128 + 32 * (kn >> 1) + 8 * qd + 4 * (kn & 1);
#pragma unroll
            for (int sm = 0; sm < 2; sm++) {
                const f32x4 sv = sm ? s1 : s0;
                const int q = qb + w * 32 + sm * 16 + l15;
                float v[4];
#pragma unroll
                for (int r = 0; r < 4; r++) {
                    float val = fmaxf(sv[r], 0.f);
                    if (need_mask && q < keyb + r) val = 0.f;
                    v[r] = val;
                }
                PK[sm][kn][0] = pack_bf16(v[0], v[1]);
                PK[sm][kn][1] = pack_bf16(v[2], v[3]);
            }
        }

        // ---- PV: pF direct from this lane's PK dwords; vF from LDS ----
#pragma unroll
        for (int kk = 0; kk < 4; kk++) {
            bf16x8 pF[2];
#pragma unroll
            for (int sm = 0; sm < 2; sm++) {
                union { unsigned dw[4]; bf16x8 v; } uu;
                uu.dw[0] = PK[sm][2 * kk + 0][0];
                uu.dw[1] = PK[sm][2 * kk + 0][1];
                uu.dw[2] = PK[sm][2 * kk + 1][0];
                uu.dw[3] = PK[sm][2 * kk + 1][1];
                pF[sm] = uu.v;
            }
#pragma unroll
            for (int sd = 0; sd < 4; sd++) {
                bf16x8 vf = *(const bf16x8*)&Vts[(sd * 16 + l15) * 128
                                                 + (((kk * 4 + qd) ^ l15) * 8)];
                o[0][sd] = __builtin_amdgcn_mfma_f32_16x16x32_bf16(pF[0], vf, o[0][sd], 0, 0, 0);
                o[1][sd] = __builtin_amdgcn_mfma_f32_16x16x32_bf16(pF[1], vf, o[1][sd], 0, 0, 0);
            }
        }
    }

    // ---- plain-store O (exclusive q-row ownership) ----
#pragma unroll
    for (int sm = 0; sm < 2; sm++)
#pragma unroll
        for (int sd = 0; sd < 4; sd++) {
            const int d = sd * 16 + l15;
#pragma unroll
            for (int r = 0; r < 4; r++) {
                const int t = qb + w * 32 + sm * 16 + qd * 4 + r;
                out[((size_t)b * T_SEQ + t) * C_EMB + h * 64 + d] = o[sm][sd][r];
            }
        }
}

extern "C" void kernel_launch(void* const* d_in, const int* in_sizes, int n_in,
                              void* d_out, int out_size, void* d_ws, size_t ws_size,
                              hipStream_t stream) {
    const float* x    = (const float*)d_in[0];
    const float* W    = (const float*)d_in[1];
    const float* bias = (const float*)d_in[2];
    float* out        = (float*)d_out;
    bf16*  ws         = (bf16*)d_ws;

    if (ws_size >= WS_NEEDED) {
        bf16* xb = ws + 3 * (size_t)WS_STRIDE;
        bf16* wb = xb + XN;
        cvt_bf16<<<dim3(CVT_GRID), dim3(256), 0, stream>>>(x, W, xb, wb);
        qkv_gemm2<<<dim3(768), dim3(256), 0, stream>>>(xb, wb, bias, ws);
    } else {
        qkv_gemm<<<dim3(768), dim3(256), 0, stream>>>(x, W, bias, ws);
    }
    attn<<<dim3(512), dim3(256), 0, stream>>>(ws, out);
}